// Round 18
// baseline (168.644 us; speedup 1.0000x reference)
//
#include <hip/hip_runtime.h>
#include <math.h>

static constexpr int CH_IN  = 128;
static constexpr int CH_HID = 128;
static constexpr int CH_OUT = 64;
static constexpr int NBLK1  = 256;   // edge-pass blocks (count & scatter)

typedef __attribute__((ext_vector_type(8))) short bf16x8;
typedef __attribute__((ext_vector_type(4))) float f32x4;

// ---------- bf16 helpers ----------

__device__ __forceinline__ unsigned short f2bf(float f) {
    unsigned int u = __float_as_uint(f);
    u = (u + 0x7fffu + ((u >> 16) & 1u)) >> 16;   // RNE
    return (unsigned short)u;
}
__device__ __forceinline__ unsigned int pack2(float lo, float hi) {
    return (unsigned int)f2bf(lo) | ((unsigned int)f2bf(hi) << 16);
}
__device__ __forceinline__ void unpack2(unsigned int u, float& lo, float& hi) {
    lo = __uint_as_float(u << 16);
    hi = __uint_as_float(u & 0xffff0000u);
}
__device__ __forceinline__ unsigned int relu2(unsigned int u) {
    unsigned int m = 0;
    if (!(u & 0x8000u)) m |= 0xffffu;
    if (!(u & 0x80000000u)) m |= 0xffff0000u;
    return u & m;
}

// accumulate 8 int8 channels from a uint2 (nm includes row scale)
__device__ __forceinline__ void gacc8(const uint2* __restrict__ hp, int stride, int s,
                                      int ci, float nm, float* acc) {
    uint2 v = hp[(size_t)s * stride + ci];
    int x = (int)v.x, y = (int)v.y;
    acc[0] = fmaf((float)(char)(x      ), nm, acc[0]);
    acc[1] = fmaf((float)(char)(x >>  8), nm, acc[1]);
    acc[2] = fmaf((float)(char)(x >> 16), nm, acc[2]);
    acc[3] = fmaf((float)(x >> 24),       nm, acc[3]);
    acc[4] = fmaf((float)(char)(y      ), nm, acc[4]);
    acc[5] = fmaf((float)(char)(y >>  8), nm, acc[5]);
    acc[6] = fmaf((float)(char)(y >> 16), nm, acc[6]);
    acc[7] = fmaf((float)(y >> 24),       nm, acc[7]);
}

// accumulate 16 int8 channels from a uint4 (nm includes row scale)
__device__ __forceinline__ void gacc16(const uint4* __restrict__ hp, int stride, int s,
                                       int chunk, float nm, float* acc) {
    uint4 v = hp[(size_t)s * stride + chunk];
    int a = (int)v.x, bq = (int)v.y, c = (int)v.z, d = (int)v.w;
    acc[ 0] = fmaf((float)(char)(a       ), nm, acc[ 0]);
    acc[ 1] = fmaf((float)(char)(a  >>  8), nm, acc[ 1]);
    acc[ 2] = fmaf((float)(char)(a  >> 16), nm, acc[ 2]);
    acc[ 3] = fmaf((float)(a  >> 24),       nm, acc[ 3]);
    acc[ 4] = fmaf((float)(char)(bq      ), nm, acc[ 4]);
    acc[ 5] = fmaf((float)(char)(bq >>  8), nm, acc[ 5]);
    acc[ 6] = fmaf((float)(char)(bq >> 16), nm, acc[ 6]);
    acc[ 7] = fmaf((float)(bq >> 24),       nm, acc[ 7]);
    acc[ 8] = fmaf((float)(char)(c       ), nm, acc[ 8]);
    acc[ 9] = fmaf((float)(char)(c  >>  8), nm, acc[ 9]);
    acc[10] = fmaf((float)(char)(c  >> 16), nm, acc[10]);
    acc[11] = fmaf((float)(c  >> 24),       nm, acc[11]);
    acc[12] = fmaf((float)(char)(d       ), nm, acc[12]);
    acc[13] = fmaf((float)(char)(d  >>  8), nm, acc[13]);
    acc[14] = fmaf((float)(char)(d  >> 16), nm, acc[14]);
    acc[15] = fmaf((float)(d  >> 24),       nm, acc[15]);
}

// unpack own int8 row-segment (uint2, 8 ch) with scale
__device__ __forceinline__ void unq8(uint2 v, float sc, float* hn) {
    int x = (int)v.x, y = (int)v.y;
    hn[0] = (float)(char)(x      ) * sc; hn[1] = (float)(char)(x >>  8) * sc;
    hn[2] = (float)(char)(x >> 16) * sc; hn[3] = (float)(x >> 24)       * sc;
    hn[4] = (float)(char)(y      ) * sc; hn[5] = (float)(char)(y >>  8) * sc;
    hn[6] = (float)(char)(y >> 16) * sc; hn[7] = (float)(y >> 24)       * sc;
}

// unpack own int8 row-segment (uint4, 16 ch) with scale
__device__ __forceinline__ void unq16(uint4 v, float sc, float* hn) {
    int a = (int)v.x, bq = (int)v.y, c = (int)v.z, d = (int)v.w;
    hn[ 0] = (float)(char)(a       ) * sc; hn[ 1] = (float)(char)(a  >>  8) * sc;
    hn[ 2] = (float)(char)(a  >> 16) * sc; hn[ 3] = (float)(a  >> 24)       * sc;
    hn[ 4] = (float)(char)(bq      ) * sc; hn[ 5] = (float)(char)(bq >>  8) * sc;
    hn[ 6] = (float)(char)(bq >> 16) * sc; hn[ 7] = (float)(bq >> 24)       * sc;
    hn[ 8] = (float)(char)(c       ) * sc; hn[ 9] = (float)(char)(c  >>  8) * sc;
    hn[10] = (float)(char)(c  >> 16) * sc; hn[11] = (float)(c  >> 24)       * sc;
    hn[12] = (float)(char)(d       ) * sc; hn[13] = (float)(char)(d  >>  8) * sc;
    hn[14] = (float)(char)(d  >> 16) * sc; hn[15] = (float)(d  >> 24)       * sc;
}

__device__ __forceinline__ int block_incl_scan_256(int v, int lane, int wid) {
    __shared__ int wtot[4];
    int s = v;
    #pragma unroll
    for (int off = 1; off < 64; off <<= 1) {
        int t = __shfl_up(s, off, 64);
        if (lane >= off) s += t;
    }
    if (lane == 63) wtot[wid] = s;
    __syncthreads();
    int woff = 0;
    for (int j = 0; j < wid; ++j) woff += wtot[j];
    return s + woff;
}

// ---------- GEMM1 body: x fp32 -> MFMA -> int8 row-scaled h1q + scl ----------

__device__ __forceinline__ void gemm128q_body(const float* __restrict__ X,
                                              const unsigned short* __restrict__ Wt,
                                              signed char* __restrict__ Hq,
                                              float* __restrict__ scl, int N, int blk) {
    constexpr int NCT = CH_HID / 16;       // 8
    __shared__ unsigned short As[64 * 136];
    const int tid = threadIdx.x;
    const int lane = tid & 63, wv = tid >> 6;
    const int row0 = blk * 64;

    #pragma unroll
    for (int j = 0; j < 8; ++j) {
        int f = j * 256 + tid;
        int row = f >> 5, col = (f & 31) * 4;
        float4 v = make_float4(0.f, 0.f, 0.f, 0.f);
        if (row0 + row < N)
            v = *reinterpret_cast<const float4*>(X + (size_t)(row0 + row) * CH_IN + col);
        uint2 p;
        p.x = pack2(v.x, v.y);
        p.y = pack2(v.z, v.w);
        *reinterpret_cast<uint2*>(&As[row * 136 + col]) = p;
    }
    __syncthreads();

    const int rw0  = wv * 16;
    const int arow = rw0 + (lane & 15);
    const int kgrp = (lane >> 4) * 8;
    f32x4 acc[NCT];
    #pragma unroll
    for (int c = 0; c < NCT; ++c) acc[c] = f32x4{0.f, 0.f, 0.f, 0.f};

    #pragma unroll
    for (int kk = 0; kk < 4; ++kk) {
        bf16x8 af = *reinterpret_cast<const bf16x8*>(&As[arow * 136 + kk * 32 + kgrp]);
        #pragma unroll
        for (int ct = 0; ct < NCT; ++ct) {
            bf16x8 bf = *reinterpret_cast<const bf16x8*>(
                Wt + (size_t)(ct * 16 + (lane & 15)) * 128 + kk * 32 + kgrp);
            acc[ct] = __builtin_amdgcn_mfma_f32_16x16x32_bf16(af, bf, acc[ct], 0, 0, 0);
        }
    }

    // per-row absmax -> scale -> int8 quantize
    const int orow0 = row0 + rw0 + (lane >> 4) * 4;
    const int ocol  = lane & 15;
    #pragma unroll
    for (int r = 0; r < 4; ++r) {
        float m = 0.f;
        #pragma unroll
        for (int ct = 0; ct < NCT; ++ct) m = fmaxf(m, fabsf(acc[ct][r]));
        m = fmaxf(m, __shfl_xor(m, 1, 64));
        m = fmaxf(m, __shfl_xor(m, 2, 64));
        m = fmaxf(m, __shfl_xor(m, 4, 64));
        m = fmaxf(m, __shfl_xor(m, 8, 64));   // row absmax across 16 col-lanes
        int row = orow0 + r;
        float inv = (m > 0.f) ? 127.f / m : 0.f;
        if (row < N) {
            if (ocol == 0) scl[row] = (m > 0.f) ? m / 127.f : 0.f;
            #pragma unroll
            for (int ct = 0; ct < NCT; ++ct)
                Hq[(size_t)row * CH_HID + ct * 16 + ocol] =
                    (signed char)__float2int_rn(acc[ct][r] * inv);
        }
    }
}

// ---------- stage 1: bucket count (LDS hist) ∥ weight transpose (extra blocks) ----------

__global__ void k_count(const int* __restrict__ ei, int* __restrict__ cnt_bk,
                        int E, int nbk, int epb,
                        const float* __restrict__ W1, unsigned short* __restrict__ w1t,
                        const float* __restrict__ W2, unsigned short* __restrict__ w2t) {
    __shared__ int bcnt[256];
    const int tid = threadIdx.x;
    if ((int)blockIdx.x < NBLK1) {
        const int b = blockIdx.x;
        bcnt[tid] = 0;
        __syncthreads();
        const int e0 = b * epb, e1 = min(E, e0 + epb);
        for (int e = e0 + tid; e < e1; e += 256)
            atomicAdd(&bcnt[ei[E + e] >> 8], 1);          // LDS atomic
        __syncthreads();
        if (tid < nbk) cnt_bk[tid * NBLK1 + b] = bcnt[tid];
    } else {
        int j = (blockIdx.x - NBLK1) * 256 + tid;         // weight transpose
        if (j < CH_HID * 128) {
            int c = j >> 7, k = j & 127;
            w1t[(size_t)c * 128 + k] = f2bf(W1[(size_t)k * CH_HID + c]);
            return;
        }
        j -= CH_HID * 128;
        if (j < CH_OUT * 128) {
            int c = j >> 7, k = j & 127;
            w2t[(size_t)c * 128 + k] = f2bf(W2[(size_t)k * CH_OUT + c]);
        }
    }
}

// ---------- stage 2: per-bucket cross-block scan ----------

__global__ void k_bscan(const int* __restrict__ cnt_bk, int* __restrict__ off_bk,
                        int* __restrict__ btot) {
    const int k = blockIdx.x, tid = threadIdx.x, lane = tid & 63, wid = tid >> 6;
    int c = cnt_bk[k * NBLK1 + tid];
    int incl = block_incl_scan_256(c, lane, wid);
    off_bk[k * NBLK1 + tid] = incl - c;                   // exclusive over blocks
    if (tid == 255) btot[k] = incl;
}

// ---------- stage 3 (fat): GEMM1(int8 out) ∥ scatter into bucket order ----------

__global__ void __launch_bounds__(256) k_fat(
        const float* __restrict__ x, const unsigned short* __restrict__ w1t,
        signed char* __restrict__ h1q, float* __restrict__ scl1, int N, int nbg,
        const int* __restrict__ ei, const float* __restrict__ w,
        const int* __restrict__ btot, const int* __restrict__ off_bk,
        uint2* __restrict__ ebuck, int E, int nbk, int epb) {
    if ((int)blockIdx.x < nbg) {
        gemm128q_body(x, w1t, h1q, scl1, N, blockIdx.x);
    } else {
        __shared__ int lcur[256];
        const int b = blockIdx.x - nbg;
        const int tid = threadIdx.x, lane = tid & 63, wid = tid >> 6;
        int v = (tid < nbk) ? btot[tid] : 0;
        int incl = block_incl_scan_256(v, lane, wid);
        if (tid < nbk) lcur[tid] = (incl - v) + off_bk[tid * NBLK1 + b];
        __syncthreads();
        const int e0 = b * epb, e1 = min(E, e0 + epb);
        for (int e = e0 + tid; e < e1; e += 256) {
            unsigned int s = (unsigned int)ei[e];
            unsigned int d = (unsigned int)ei[E + e];
            int pos = atomicAdd(&lcur[d >> 8], 1);        // LDS atomic
            ebuck[pos] = make_uint2((d << 16) | s, __float_as_uint(w[e]));
        }
    }
}

// ---------- GEMM2: bf16 out1 (fused relu) -> MFMA -> int8 row-scaled h2q + scl2 ----------

__global__ void __launch_bounds__(256) k_gemm2(const unsigned short* __restrict__ X,
        const unsigned short* __restrict__ Wt, signed char* __restrict__ Hq,
        float* __restrict__ scl, int N) {
    constexpr int COLS = CH_OUT, NCT = COLS / 16;         // 4
    __shared__ unsigned short As[64 * 136];
    const int tid = threadIdx.x;
    const int lane = tid & 63, wv = tid >> 6;
    const int row0 = blockIdx.x * 64;

    #pragma unroll
    for (int j = 0; j < 4; ++j) {
        int f = j * 256 + tid;
        int row = f >> 4, col = (f & 15) * 8;
        uint4 v = make_uint4(0u, 0u, 0u, 0u);
        if (row0 + row < N) {
            v = *reinterpret_cast<const uint4*>(X + (size_t)(row0 + row) * CH_IN + col);
            v.x = relu2(v.x); v.y = relu2(v.y);
            v.z = relu2(v.z); v.w = relu2(v.w);
        }
        *reinterpret_cast<uint4*>(&As[row * 136 + col]) = v;
    }
    __syncthreads();

    const int rw0  = wv * 16;
    const int arow = rw0 + (lane & 15);
    const int kgrp = (lane >> 4) * 8;
    f32x4 acc[NCT];
    #pragma unroll
    for (int c = 0; c < NCT; ++c) acc[c] = f32x4{0.f, 0.f, 0.f, 0.f};

    #pragma unroll
    for (int kk = 0; kk < 4; ++kk) {
        bf16x8 af = *reinterpret_cast<const bf16x8*>(&As[arow * 136 + kk * 32 + kgrp]);
        #pragma unroll
        for (int ct = 0; ct < NCT; ++ct) {
            bf16x8 bf = *reinterpret_cast<const bf16x8*>(
                Wt + (size_t)(ct * 16 + (lane & 15)) * 128 + kk * 32 + kgrp);
            acc[ct] = __builtin_amdgcn_mfma_f32_16x16x32_bf16(af, bf, acc[ct], 0, 0, 0);
        }
    }

    const int orow0 = row0 + rw0 + (lane >> 4) * 4;
    const int ocol  = lane & 15;
    #pragma unroll
    for (int r = 0; r < 4; ++r) {
        float m = 0.f;
        #pragma unroll
        for (int ct = 0; ct < NCT; ++ct) m = fmaxf(m, fabsf(acc[ct][r]));
        m = fmaxf(m, __shfl_xor(m, 1, 64));
        m = fmaxf(m, __shfl_xor(m, 2, 64));
        m = fmaxf(m, __shfl_xor(m, 4, 64));
        m = fmaxf(m, __shfl_xor(m, 8, 64));
        int row = orow0 + r;
        float inv = (m > 0.f) ? 127.f / m : 0.f;
        if (row < N) {
            if (ocol == 0) scl[row] = (m > 0.f) ? m / 127.f : 0.f;
            #pragma unroll
            for (int ct = 0; ct < NCT; ++ct)
                Hq[(size_t)row * COLS + ct * 16 + ocol] =
                    (signed char)__float2int_rn(acc[ct][r] * inv);
        }
    }
}

// ---------- stage 4: per-bucket CSR + fused weighted-degree/dinv ----------

__global__ void k_csr(const uint2* __restrict__ ebuck, const int* __restrict__ btot,
                      int* __restrict__ rowptr, float* __restrict__ dinv,
                      int2* __restrict__ epack, int N, int nbk) {
    __shared__ int ncnt[256];
    __shared__ float wsm[256];
    __shared__ int ebeg_s, eend_s;
    const int k = blockIdx.x, tid = threadIdx.x, lane = tid & 63, wid = tid >> 6;
    int v = (tid < nbk) ? btot[tid] : 0;
    int incl0 = block_incl_scan_256(v, lane, wid);
    if (tid == k) { ebeg_s = incl0 - v; eend_s = incl0; }
    ncnt[tid] = 0; wsm[tid] = 0.f;
    __syncthreads();
    const int ebeg = ebeg_s, eend = eend_s;
    for (int i = ebeg + tid; i < eend; i += 256) {
        uint2 p = ebuck[i];
        int dl = (p.x >> 16) & 255;
        atomicAdd(&ncnt[dl], 1);
        atomicAdd(&wsm[dl], __uint_as_float(p.y));        // LDS float atomic
    }
    __syncthreads();
    int c = ncnt[tid];
    int incl = block_incl_scan_256(c, lane, wid);
    const int nd = k * 256 + tid;
    if (nd < N) {
        rowptr[nd + 1] = ebeg + incl;
        dinv[nd] = rsqrtf(1.0f + wsm[tid]);
    }
    if (k == 0 && tid == 0) rowptr[0] = 0;
    __syncthreads();
    ncnt[tid] = ebeg + incl - c;                          // node cursor (global pos)
    __syncthreads();
    for (int i = ebeg + tid; i < eend; i += 256) {
        uint2 p = ebuck[i];
        int dl = (p.x >> 16) & 255;
        int pos = atomicAdd(&ncnt[dl], 1);
        epack[pos] = make_int2((int)(p.x & 0xFFFFu), (int)p.y);
    }
}

// ---------- stage 5: aggregation-1 over int8 h1q -> bf16 out1 ----------
// 2 WAVES PER NODE (channel halves): wave gw -> node=gw>>1, half=gw&1.
// lane = 16*... lane: g = lane>>2 (16 edge subgroups), ci = lane&3 (uint4 of half-row).
// One load instr = 16 edges x 64B half-rows = 1KB. 2x wave TLP vs 1-wave version.

__global__ void k_agg128(const int* __restrict__ rowptr, const int2* __restrict__ epack,
                         const float* __restrict__ dinv, const float* __restrict__ scl,
                         const signed char* __restrict__ hq,
                         const float* __restrict__ b, unsigned short* __restrict__ out, int N) {
    const int gw   = (blockIdx.x * blockDim.x + threadIdx.x) >> 6;
    const int node = gw >> 1;
    const int half = gw & 1;
    const int lane = threadIdx.x & 63;
    if (node >= N) return;
    const int beg = rowptr[node], end = rowptr[node + 1];
    const float dd = dinv[node];
    const int g  = lane >> 2;              // 0..15 edge subgroup
    const int ci = lane & 3;               // uint4 within half-row
    const int chunk = half * 4 + ci;       // uint4 index within full 128-int8 row
    const uint4* hp = (const uint4*)hq;    // 8 uint4 per row

    float acc[16];
    #pragma unroll
    for (int q = 0; q < 16; ++q) acc[q] = 0.f;

    for (int i0 = beg; i0 < end; i0 += 64) {
        const int m = min(64, end - i0);
        int s_l = 0; float nm_l = 0.f;
        if (lane < m) {
            int2 p = epack[i0 + lane];
            s_l = p.x;
            nm_l = __int_as_float(p.y) * dinv[p.x] * scl[p.x];  // fold row scale
        }
        int j = 0;
        if (m == 64) {                                    // full chunk: 4 loads in flight
            #pragma unroll
            for (int kk = 0; kk < 4; ++kk) {
                int idx = 16 * kk + g;
                int   s  = __shfl(s_l, idx, 64);
                float nm = __shfl(nm_l, idx, 64);
                gacc16(hp, 8, s, chunk, nm, acc);
            }
            j = 64;
        }
        for (; j < m; j += 16) {                          // rounds of 16 (padded tail)
            int idx = j + g;
            int   s  = __shfl(s_l, idx, 64);
            float nm = __shfl(nm_l, idx, 64);
            gacc16(hp, 8, s, chunk, nm, acc);
        }
    }
    // combine 16 edge subgroups (lane bits 2..5)
    #pragma unroll
    for (int q = 0; q < 16; ++q) {
        acc[q] += __shfl_xor(acc[q], 4, 64);
        acc[q] += __shfl_xor(acc[q], 8, 64);
        acc[q] += __shfl_xor(acc[q], 16, 64);
        acc[q] += __shfl_xor(acc[q], 32, 64);
    }
    // self + bias for channels [half*64 + ci*16, +16)
    float hn[16];
    unq16(hp[(size_t)node * 8 + chunk], scl[node], hn);
    const float* bp = b + half * 64 + ci * 16;
    float res[16];
    #pragma unroll
    for (int q = 0; q < 16; ++q)
        res[q] = fmaf(acc[q], dd, fmaf(hn[q], dd * dd, bp[q]));
    if (g == 0) {                                         // 4 lanes x 32B (16 bf16)
        unsigned int* ob = (unsigned int*)out + (size_t)node * 64 + half * 32 + ci * 8;
        uint4 o0, o1;
        o0.x = pack2(res[0],  res[1]);  o0.y = pack2(res[2],  res[3]);
        o0.z = pack2(res[4],  res[5]);  o0.w = pack2(res[6],  res[7]);
        o1.x = pack2(res[8],  res[9]);  o1.y = pack2(res[10], res[11]);
        o1.z = pack2(res[12], res[13]); o1.w = pack2(res[14], res[15]);
        *reinterpret_cast<uint4*>(ob)     = o0;
        *reinterpret_cast<uint4*>(ob + 4) = o1;
    }
}

// ---------- stage 7: layer-2 aggregation over int8 h2q + fused log_softmax ----------

__global__ void k_agg64(const int* __restrict__ rowptr, const int2* __restrict__ epack,
                        const float* __restrict__ dinv, const float* __restrict__ scl,
                        const signed char* __restrict__ hq,
                        const float* __restrict__ b, float* __restrict__ out, int N) {
    const int node = (blockIdx.x * blockDim.x + threadIdx.x) >> 6;
    const int lane = threadIdx.x & 63;
    if (node >= N) return;
    const int beg = rowptr[node], end = rowptr[node + 1];
    const float dd = dinv[node];
    const int g  = lane >> 3;              // 0..7
    const int ci = lane & 7;               // channels [8ci, 8ci+8)
    const uint2* hp = (const uint2*)hq;    // 8 uint2 per row (64 int8)

    float acc[8];
    #pragma unroll
    for (int q = 0; q < 8; ++q) acc[q] = 0.f;

    for (int i0 = beg; i0 < end; i0 += 64) {
        const int m = min(64, end - i0);
        int s_l = 0; float nm_l = 0.f;
        if (lane < m) {
            int2 p = epack[i0 + lane];
            s_l = p.x;
            nm_l = __int_as_float(p.y) * dinv[p.x] * scl[p.x];  // fold row scale
        }
        int j = 0;
        for (; j + 32 <= m; j += 32) {                // 4 gathers in flight
            #pragma unroll
            for (int kk = 0; kk < 4; ++kk) {
                int idx = j + 8 * kk + g;
                int   s  = __shfl(s_l, idx, 64);
                float nm = __shfl(nm_l, idx, 64);
                gacc8(hp, 8, s, ci, nm, acc);
            }
        }
        for (; j < m; j += 8) {                       // tail: <=7 padded edges
            int idx = j + g;
            int   s  = __shfl(s_l, idx, 64);
            float nm = __shfl(nm_l, idx, 64);
            gacc8(hp, 8, s, ci, nm, acc);
        }
    }
    #pragma unroll
    for (int q = 0; q < 8; ++q) {
        acc[q] += __shfl_xor(acc[q], 8, 64);
        acc[q] += __shfl_xor(acc[q], 16, 64);
        acc[q] += __shfl_xor(acc[q], 32, 64);
    }
    // self term from own quantized row
    float hn[8];
    unq8(hp[(size_t)node * 8 + ci], scl[node], hn);
    float4 b0 = *reinterpret_cast<const float4*>(b + 8 * ci);
    float4 b1v = *reinterpret_cast<const float4*>(b + 8 * ci + 4);
    const float bb[8] = {b0.x, b0.y, b0.z, b0.w, b1v.x, b1v.y, b1v.z, b1v.w};
    float res[8];
    #pragma unroll
    for (int q = 0; q < 8; ++q)
        res[q] = fmaf(acc[q], dd, fmaf(hn[q], dd * dd, bb[q]));

    float mx = res[0];
    #pragma unroll
    for (int q = 1; q < 8; ++q) mx = fmaxf(mx, res[q]);
    mx = fmaxf(mx, __shfl_xor(mx, 1, 64));
    mx = fmaxf(mx, __shfl_xor(mx, 2, 64));
    mx = fmaxf(mx, __shfl_xor(mx, 4, 64));
    float sm = 0.f;
    #pragma unroll
    for (int q = 0; q < 8; ++q) sm += expf(res[q] - mx);
    sm += __shfl_xor(sm, 1, 64);
    sm += __shfl_xor(sm, 2, 64);
    sm += __shfl_xor(sm, 4, 64);
    float lse = mx + logf(sm);
    if (g == 0) {
        float4 o0 = make_float4(res[0] - lse, res[1] - lse, res[2] - lse, res[3] - lse);
        float4 o1 = make_float4(res[4] - lse, res[5] - lse, res[6] - lse, res[7] - lse);
        *reinterpret_cast<float4*>(out + (size_t)node * 64 + 8 * ci)     = o0;
        *reinterpret_cast<float4*>(out + (size_t)node * 64 + 8 * ci + 4) = o1;
    }
}

extern "C" void kernel_launch(void* const* d_in, const int* in_sizes, int n_in,
                              void* d_out, int out_size, void* d_ws, size_t ws_size,
                              hipStream_t stream) {
    const float* x  = (const float*)d_in[0];
    const int*   ei = (const int*)d_in[1];     // [2,E]: src = ei[e], dst = ei[E+e]
    const float* w  = (const float*)d_in[2];
    const float* W1 = (const float*)d_in[3];
    const float* b1 = (const float*)d_in[4];
    const float* W2 = (const float*)d_in[5];
    const float* b2 = (const float*)d_in[6];
    float* out = (float*)d_out;

    const int N = in_sizes[0] / CH_IN;         // 50000 (< 65536: 16-bit packing valid)
    const int E = in_sizes[2];
    const int NBK = (N + 255) >> 8;            // buckets of 256 nodes (196)
    const int EPB = (E + NBLK1 - 1) / NBLK1;   // edges per count/scatter block
    const int WTB = (CH_HID * 128 + CH_OUT * 128 + 255) / 256;  // transpose blocks (96)

    // workspace carve (float units; uint2/int2 8B-aligned, bf16/int8 arrays 16B-aligned)
    float* ws0   = (float*)d_ws;
    float* ws    = ws0;
    float* dinv  = ws;               ws += N;
    float* scl1  = ws;               ws += N;
    float* scl2  = ws;               ws += N;
    int*   rowptr= (int*)ws;         ws += (N + 2);
    int*   cnt_bk= (int*)ws;         ws += 256 * NBLK1;
    int*   off_bk= (int*)ws;         ws += 256 * NBLK1;
    int*   btot  = (int*)ws;         ws += 256;
    uint2* ebuck = (uint2*)ws;       ws += (size_t)2 * E;
    int2*  epack = (int2*)ws;        ws += (size_t)2 * E;
    { size_t off = (size_t)(ws - ws0) & 3; if (off) ws += 4 - off; }   // 16B align
    unsigned short* w1t  = (unsigned short*)ws;  ws += (size_t)CH_HID * 128 / 2;
    unsigned short* w2t  = (unsigned short*)ws;  ws += (size_t)CH_OUT * 128 / 2;
    signed char*    h1q  = (signed char*)ws;     ws += (size_t)N * CH_HID / 4;   // int8 [N,128]
    unsigned short* out1 = (unsigned short*)ws;  ws += (size_t)N * CH_HID / 2;   // bf16 [N,128]
    signed char*    h2q  = (signed char*)ws;     ws += (size_t)N * CH_OUT / 4;   // int8 [N,64]

    const int B = 256;

    // 1) bucket count (atomic-free) ∥ weight transposes
    k_count<<<NBLK1 + WTB, B, 0, stream>>>(ei, cnt_bk, E, NBK, EPB, W1, w1t, W2, w2t);

    // 2) per-bucket cross-block scan
    k_bscan<<<NBK, 256, 0, stream>>>(cnt_bk, off_bk, btot);

    // 3) GEMM1 (int8 row-scaled out) co-scheduled with bucket scatter
    {
        const int nbg = (N + 63) / 64;
        k_fat<<<nbg + NBLK1, B, 0, stream>>>(x, w1t, h1q, scl1, N, nbg,
                                             ei, w, btot, off_bk, ebuck, E, NBK, EPB);
    }

    // 4) per-bucket CSR + dinv + final epack
    k_csr<<<NBK, 256, 0, stream>>>(ebuck, btot, rowptr, dinv, epack, N, NBK);

    // 5) out1 = b1 + self + neighbor aggregate over int8 h1q (2 waves/node, 16B gathers)
    {
        const size_t waves = (size_t)N * 2;
        k_agg128<<<(waves * 64 + B - 1) / B, B, 0, stream>>>(rowptr, epack, dinv, scl1, h1q, b1, out1, N);
    }

    // 6) h2q = int8(relu(out1) @ W2) row-scaled
    k_gemm2<<<(N + 63) / 64, 256, 0, stream>>>(out1, w2t, h2q, scl2, N);

    // 7) out = log_softmax(b2 + self + aggregate over int8 h2q), fp32 into d_out
    k_agg64<<<(N * 64 + B - 1) / B, B, 0, stream>>>(rowptr, epack, dinv, scl2, h2q, b2, out, N);
}

// Round 19
// 125.906 us; speedup vs baseline: 1.3394x; 1.3394x over previous
//
#include <hip/hip_runtime.h>
#include <math.h>

static constexpr int CH_IN  = 128;
static constexpr int CH_HID = 128;
static constexpr int CH_OUT = 64;
static constexpr int NBLK1  = 256;   // edge-pass blocks (count & scatter)

typedef __attribute__((ext_vector_type(8))) short bf16x8;
typedef __attribute__((ext_vector_type(4))) float f32x4;

// ---------- bf16 helpers ----------

__device__ __forceinline__ unsigned short f2bf(float f) {
    unsigned int u = __float_as_uint(f);
    u = (u + 0x7fffu + ((u >> 16) & 1u)) >> 16;   // RNE
    return (unsigned short)u;
}
__device__ __forceinline__ unsigned int pack2(float lo, float hi) {
    return (unsigned int)f2bf(lo) | ((unsigned int)f2bf(hi) << 16);
}
__device__ __forceinline__ void unpack2(unsigned int u, float& lo, float& hi) {
    lo = __uint_as_float(u << 16);
    hi = __uint_as_float(u & 0xffff0000u);
}
__device__ __forceinline__ unsigned int relu2(unsigned int u) {
    unsigned int m = 0;
    if (!(u & 0x8000u)) m |= 0xffffu;
    if (!(u & 0x80000000u)) m |= 0xffff0000u;
    return u & m;
}

// accumulate 8 int8 channels from a uint2 (nm includes row scale)
__device__ __forceinline__ void gacc8(const uint2* __restrict__ hp, int stride, int s,
                                      int ci, float nm, float* acc) {
    uint2 v = hp[(size_t)s * stride + ci];
    int x = (int)v.x, y = (int)v.y;
    acc[0] = fmaf((float)(char)(x      ), nm, acc[0]);
    acc[1] = fmaf((float)(char)(x >>  8), nm, acc[1]);
    acc[2] = fmaf((float)(char)(x >> 16), nm, acc[2]);
    acc[3] = fmaf((float)(x >> 24),       nm, acc[3]);
    acc[4] = fmaf((float)(char)(y      ), nm, acc[4]);
    acc[5] = fmaf((float)(char)(y >>  8), nm, acc[5]);
    acc[6] = fmaf((float)(char)(y >> 16), nm, acc[6]);
    acc[7] = fmaf((float)(y >> 24),       nm, acc[7]);
}

// unpack own int8 row-segment (uint2, 8 ch) scaled by sc
__device__ __forceinline__ void unq8(uint2 v, float sc, float* hn) {
    int x = (int)v.x, y = (int)v.y;
    hn[0] = (float)(char)(x      ) * sc; hn[1] = (float)(char)(x >>  8) * sc;
    hn[2] = (float)(char)(x >> 16) * sc; hn[3] = (float)(x >> 24)       * sc;
    hn[4] = (float)(char)(y      ) * sc; hn[5] = (float)(char)(y >>  8) * sc;
    hn[6] = (float)(char)(y >> 16) * sc; hn[7] = (float)(y >> 24)       * sc;
}

__device__ __forceinline__ int block_incl_scan_256(int v, int lane, int wid) {
    __shared__ int wtot[4];
    int s = v;
    #pragma unroll
    for (int off = 1; off < 64; off <<= 1) {
        int t = __shfl_up(s, off, 64);
        if (lane >= off) s += t;
    }
    if (lane == 63) wtot[wid] = s;
    __syncthreads();
    int woff = 0;
    for (int j = 0; j < wid; ++j) woff += wtot[j];
    return s + woff;
}

// ---------- GEMM1 body: x fp32 -> MFMA -> int8 row-scaled h1q + scl ----------

__device__ __forceinline__ void gemm128q_body(const float* __restrict__ X,
                                              const unsigned short* __restrict__ Wt,
                                              signed char* __restrict__ Hq,
                                              float* __restrict__ scl, int N, int blk) {
    constexpr int NCT = CH_HID / 16;       // 8
    __shared__ unsigned short As[64 * 136];
    const int tid = threadIdx.x;
    const int lane = tid & 63, wv = tid >> 6;
    const int row0 = blk * 64;

    #pragma unroll
    for (int j = 0; j < 8; ++j) {
        int f = j * 256 + tid;
        int row = f >> 5, col = (f & 31) * 4;
        float4 v = make_float4(0.f, 0.f, 0.f, 0.f);
        if (row0 + row < N)
            v = *reinterpret_cast<const float4*>(X + (size_t)(row0 + row) * CH_IN + col);
        uint2 p;
        p.x = pack2(v.x, v.y);
        p.y = pack2(v.z, v.w);
        *reinterpret_cast<uint2*>(&As[row * 136 + col]) = p;
    }
    __syncthreads();

    const int rw0  = wv * 16;
    const int arow = rw0 + (lane & 15);
    const int kgrp = (lane >> 4) * 8;
    f32x4 acc[NCT];
    #pragma unroll
    for (int c = 0; c < NCT; ++c) acc[c] = f32x4{0.f, 0.f, 0.f, 0.f};

    #pragma unroll
    for (int kk = 0; kk < 4; ++kk) {
        bf16x8 af = *reinterpret_cast<const bf16x8*>(&As[arow * 136 + kk * 32 + kgrp]);
        #pragma unroll
        for (int ct = 0; ct < NCT; ++ct) {
            bf16x8 bf = *reinterpret_cast<const bf16x8*>(
                Wt + (size_t)(ct * 16 + (lane & 15)) * 128 + kk * 32 + kgrp);
            acc[ct] = __builtin_amdgcn_mfma_f32_16x16x32_bf16(af, bf, acc[ct], 0, 0, 0);
        }
    }

    // per-row absmax -> scale -> int8 quantize
    const int orow0 = row0 + rw0 + (lane >> 4) * 4;
    const int ocol  = lane & 15;
    #pragma unroll
    for (int r = 0; r < 4; ++r) {
        float m = 0.f;
        #pragma unroll
        for (int ct = 0; ct < NCT; ++ct) m = fmaxf(m, fabsf(acc[ct][r]));
        m = fmaxf(m, __shfl_xor(m, 1, 64));
        m = fmaxf(m, __shfl_xor(m, 2, 64));
        m = fmaxf(m, __shfl_xor(m, 4, 64));
        m = fmaxf(m, __shfl_xor(m, 8, 64));   // row absmax across 16 col-lanes
        int row = orow0 + r;
        float inv = (m > 0.f) ? 127.f / m : 0.f;
        if (row < N) {
            if (ocol == 0) scl[row] = (m > 0.f) ? m / 127.f : 0.f;
            #pragma unroll
            for (int ct = 0; ct < NCT; ++ct)
                Hq[(size_t)row * CH_HID + ct * 16 + ocol] =
                    (signed char)__float2int_rn(acc[ct][r] * inv);
        }
    }
}

// ---------- stage 1: bucket count (LDS hist) ∥ weight transpose (extra blocks) ----------

__global__ void k_count(const int* __restrict__ ei, int* __restrict__ cnt_bk,
                        int E, int nbk, int epb,
                        const float* __restrict__ W1, unsigned short* __restrict__ w1t,
                        const float* __restrict__ W2, unsigned short* __restrict__ w2t) {
    __shared__ int bcnt[256];
    const int tid = threadIdx.x;
    if ((int)blockIdx.x < NBLK1) {
        const int b = blockIdx.x;
        bcnt[tid] = 0;
        __syncthreads();
        const int e0 = b * epb, e1 = min(E, e0 + epb);
        for (int e = e0 + tid; e < e1; e += 256)
            atomicAdd(&bcnt[ei[E + e] >> 8], 1);          // LDS atomic
        __syncthreads();
        if (tid < nbk) cnt_bk[tid * NBLK1 + b] = bcnt[tid];
    } else {
        int j = (blockIdx.x - NBLK1) * 256 + tid;         // weight transpose
        if (j < CH_HID * 128) {
            int c = j >> 7, k = j & 127;
            w1t[(size_t)c * 128 + k] = f2bf(W1[(size_t)k * CH_HID + c]);
            return;
        }
        j -= CH_HID * 128;
        if (j < CH_OUT * 128) {
            int c = j >> 7, k = j & 127;
            w2t[(size_t)c * 128 + k] = f2bf(W2[(size_t)k * CH_OUT + c]);
        }
    }
}

// ---------- stage 2: per-bucket cross-block scan ----------

__global__ void k_bscan(const int* __restrict__ cnt_bk, int* __restrict__ off_bk,
                        int* __restrict__ btot) {
    const int k = blockIdx.x, tid = threadIdx.x, lane = tid & 63, wid = tid >> 6;
    int c = cnt_bk[k * NBLK1 + tid];
    int incl = block_incl_scan_256(c, lane, wid);
    off_bk[k * NBLK1 + tid] = incl - c;                   // exclusive over blocks
    if (tid == 255) btot[k] = incl;
}

// ---------- stage 3 (fat): GEMM1(int8 out) ∥ scatter into bucket order ----------

__global__ void __launch_bounds__(256) k_fat(
        const float* __restrict__ x, const unsigned short* __restrict__ w1t,
        signed char* __restrict__ h1q, float* __restrict__ scl1, int N, int nbg,
        const int* __restrict__ ei, const float* __restrict__ w,
        const int* __restrict__ btot, const int* __restrict__ off_bk,
        uint2* __restrict__ ebuck, int E, int nbk, int epb) {
    if ((int)blockIdx.x < nbg) {
        gemm128q_body(x, w1t, h1q, scl1, N, blockIdx.x);
    } else {
        __shared__ int lcur[256];
        const int b = blockIdx.x - nbg;
        const int tid = threadIdx.x, lane = tid & 63, wid = tid >> 6;
        int v = (tid < nbk) ? btot[tid] : 0;
        int incl = block_incl_scan_256(v, lane, wid);
        if (tid < nbk) lcur[tid] = (incl - v) + off_bk[tid * NBLK1 + b];
        __syncthreads();
        const int e0 = b * epb, e1 = min(E, e0 + epb);
        for (int e = e0 + tid; e < e1; e += 256) {
            unsigned int s = (unsigned int)ei[e];
            unsigned int d = (unsigned int)ei[E + e];
            int pos = atomicAdd(&lcur[d >> 8], 1);        // LDS atomic
            ebuck[pos] = make_uint2((d << 16) | s, __float_as_uint(w[e]));
        }
    }
}

// ---------- GEMM2: bf16 out1 (fused relu) -> MFMA -> int8 h2q + ds2 = scl2*dinv ----------

__global__ void __launch_bounds__(256) k_gemm2(const unsigned short* __restrict__ X,
        const unsigned short* __restrict__ Wt, const float* __restrict__ dinv,
        signed char* __restrict__ Hq, float* __restrict__ ds2, int N) {
    constexpr int COLS = CH_OUT, NCT = COLS / 16;         // 4
    __shared__ unsigned short As[64 * 136];
    const int tid = threadIdx.x;
    const int lane = tid & 63, wv = tid >> 6;
    const int row0 = blockIdx.x * 64;

    #pragma unroll
    for (int j = 0; j < 4; ++j) {
        int f = j * 256 + tid;
        int row = f >> 4, col = (f & 15) * 8;
        uint4 v = make_uint4(0u, 0u, 0u, 0u);
        if (row0 + row < N) {
            v = *reinterpret_cast<const uint4*>(X + (size_t)(row0 + row) * CH_IN + col);
            v.x = relu2(v.x); v.y = relu2(v.y);
            v.z = relu2(v.z); v.w = relu2(v.w);
        }
        *reinterpret_cast<uint4*>(&As[row * 136 + col]) = v;
    }
    __syncthreads();

    const int rw0  = wv * 16;
    const int arow = rw0 + (lane & 15);
    const int kgrp = (lane >> 4) * 8;
    f32x4 acc[NCT];
    #pragma unroll
    for (int c = 0; c < NCT; ++c) acc[c] = f32x4{0.f, 0.f, 0.f, 0.f};

    #pragma unroll
    for (int kk = 0; kk < 4; ++kk) {
        bf16x8 af = *reinterpret_cast<const bf16x8*>(&As[arow * 136 + kk * 32 + kgrp]);
        #pragma unroll
        for (int ct = 0; ct < NCT; ++ct) {
            bf16x8 bf = *reinterpret_cast<const bf16x8*>(
                Wt + (size_t)(ct * 16 + (lane & 15)) * 128 + kk * 32 + kgrp);
            acc[ct] = __builtin_amdgcn_mfma_f32_16x16x32_bf16(af, bf, acc[ct], 0, 0, 0);
        }
    }

    const int orow0 = row0 + rw0 + (lane >> 4) * 4;
    const int ocol  = lane & 15;
    #pragma unroll
    for (int r = 0; r < 4; ++r) {
        float m = 0.f;
        #pragma unroll
        for (int ct = 0; ct < NCT; ++ct) m = fmaxf(m, fabsf(acc[ct][r]));
        m = fmaxf(m, __shfl_xor(m, 1, 64));
        m = fmaxf(m, __shfl_xor(m, 2, 64));
        m = fmaxf(m, __shfl_xor(m, 4, 64));
        m = fmaxf(m, __shfl_xor(m, 8, 64));
        int row = orow0 + r;
        float inv = (m > 0.f) ? 127.f / m : 0.f;
        if (row < N) {
            if (ocol == 0) ds2[row] = ((m > 0.f) ? m / 127.f : 0.f) * dinv[row];
            #pragma unroll
            for (int ct = 0; ct < NCT; ++ct)
                Hq[(size_t)row * COLS + ct * 16 + ocol] =
                    (signed char)__float2int_rn(acc[ct][r] * inv);
        }
    }
}

// ---------- stage 4: per-bucket CSR + fused degree/dinv + ds1 = dinv*scl1 ----------

__global__ void k_csr(const uint2* __restrict__ ebuck, const int* __restrict__ btot,
                      const float* __restrict__ scl1, int* __restrict__ rowptr,
                      float* __restrict__ dinv, float* __restrict__ ds1,
                      int2* __restrict__ epack, int N, int nbk) {
    __shared__ int ncnt[256];
    __shared__ float wsm[256];
    __shared__ int ebeg_s, eend_s;
    const int k = blockIdx.x, tid = threadIdx.x, lane = tid & 63, wid = tid >> 6;
    int v = (tid < nbk) ? btot[tid] : 0;
    int incl0 = block_incl_scan_256(v, lane, wid);
    if (tid == k) { ebeg_s = incl0 - v; eend_s = incl0; }
    ncnt[tid] = 0; wsm[tid] = 0.f;
    __syncthreads();
    const int ebeg = ebeg_s, eend = eend_s;
    for (int i = ebeg + tid; i < eend; i += 256) {
        uint2 p = ebuck[i];
        int dl = (p.x >> 16) & 255;
        atomicAdd(&ncnt[dl], 1);
        atomicAdd(&wsm[dl], __uint_as_float(p.y));        // LDS float atomic
    }
    __syncthreads();
    int c = ncnt[tid];
    int incl = block_incl_scan_256(c, lane, wid);
    const int nd = k * 256 + tid;
    if (nd < N) {
        rowptr[nd + 1] = ebeg + incl;
        float dv = rsqrtf(1.0f + wsm[tid]);
        dinv[nd] = dv;
        ds1[nd] = dv * scl1[nd];
    }
    if (k == 0 && tid == 0) rowptr[0] = 0;
    __syncthreads();
    ncnt[tid] = ebeg + incl - c;                          // node cursor (global pos)
    __syncthreads();
    for (int i = ebeg + tid; i < eend; i += 256) {
        uint2 p = ebuck[i];
        int dl = (p.x >> 16) & 255;
        int pos = atomicAdd(&ncnt[dl], 1);
        epack[pos] = make_int2((int)(p.x & 0xFFFFu), (int)p.y);
    }
}

// ---------- stage 5: aggregation-1 over int8 h1q (wave per node) -> bf16 out1 ----------
// nm = w * ds1[src];  res = (acc + q8_node*ds1[node]) * dd + b

__global__ void k_agg128(const int* __restrict__ rowptr, const int2* __restrict__ epack,
                         const float* __restrict__ dinv, const float* __restrict__ ds1,
                         const signed char* __restrict__ hq,
                         const float* __restrict__ b, unsigned short* __restrict__ out, int N) {
    const int node = (blockIdx.x * blockDim.x + threadIdx.x) >> 6;
    const int lane = threadIdx.x & 63;
    if (node >= N) return;
    const int beg = rowptr[node], end = rowptr[node + 1];
    const float dd = dinv[node];
    const int g  = lane >> 4;              // 0..3
    const int ci = lane & 15;              // channels [8ci, 8ci+8)
    const uint2* hp = (const uint2*)hq;    // 16 uint2 per row (128 int8)

    float acc[8];
    #pragma unroll
    for (int q = 0; q < 8; ++q) acc[q] = 0.f;

    for (int i0 = beg; i0 < end; i0 += 64) {
        const int m = min(64, end - i0);
        int s_l = 0; float nm_l = 0.f;
        if (lane < m) {
            int2 p = epack[i0 + lane];
            s_l = p.x;
            nm_l = __int_as_float(p.y) * ds1[p.x];    // single L2-hot gather
        }
        int j = 0;
        for (; j + 16 <= m; j += 16) {                // 4 gathers in flight
            #pragma unroll
            for (int kk = 0; kk < 4; ++kk) {
                int idx = j + 4 * kk + g;
                int   s  = __shfl(s_l, idx, 64);
                float nm = __shfl(nm_l, idx, 64);
                gacc8(hp, 16, s, ci, nm, acc);
            }
        }
        for (; j < m; j += 4) {                       // tail: <=3 padded edges
            int idx = j + g;
            int   s  = __shfl(s_l, idx, 64);
            float nm = __shfl(nm_l, idx, 64);
            gacc8(hp, 16, s, ci, nm, acc);
        }
    }
    #pragma unroll
    for (int q = 0; q < 8; ++q) {
        acc[q] += __shfl_xor(acc[q], 16, 64);
        acc[q] += __shfl_xor(acc[q], 32, 64);
    }
    // self term folded: hn = q8 * ds1[node]; res = (acc + hn) * dd + b
    float hn[8];
    unq8(hp[(size_t)node * 16 + ci], ds1[node], hn);
    float4 b0 = *reinterpret_cast<const float4*>(b + 8 * ci);
    float4 b1v = *reinterpret_cast<const float4*>(b + 8 * ci + 4);
    const float bb[8] = {b0.x, b0.y, b0.z, b0.w, b1v.x, b1v.y, b1v.z, b1v.w};
    float res[8];
    #pragma unroll
    for (int q = 0; q < 8; ++q)
        res[q] = fmaf(acc[q] + hn[q], dd, bb[q]);
    if (g == 0) {
        uint4 o;
        o.x = pack2(res[0], res[1]); o.y = pack2(res[2], res[3]);
        o.z = pack2(res[4], res[5]); o.w = pack2(res[6], res[7]);
        ((uint4*)out)[(size_t)node * 16 + ci] = o;
    }
}

// ---------- stage 7: layer-2 aggregation over int8 h2q + fused log_softmax ----------

__global__ void k_agg64(const int* __restrict__ rowptr, const int2* __restrict__ epack,
                        const float* __restrict__ dinv, const float* __restrict__ ds2,
                        const signed char* __restrict__ hq,
                        const float* __restrict__ b, float* __restrict__ out, int N) {
    const int node = (blockIdx.x * blockDim.x + threadIdx.x) >> 6;
    const int lane = threadIdx.x & 63;
    if (node >= N) return;
    const int beg = rowptr[node], end = rowptr[node + 1];
    const float dd = dinv[node];
    const int g  = lane >> 3;              // 0..7
    const int ci = lane & 7;               // channels [8ci, 8ci+8)
    const uint2* hp = (const uint2*)hq;    // 8 uint2 per row (64 int8)

    float acc[8];
    #pragma unroll
    for (int q = 0; q < 8; ++q) acc[q] = 0.f;

    for (int i0 = beg; i0 < end; i0 += 64) {
        const int m = min(64, end - i0);
        int s_l = 0; float nm_l = 0.f;
        if (lane < m) {
            int2 p = epack[i0 + lane];
            s_l = p.x;
            nm_l = __int_as_float(p.y) * ds2[p.x];    // single L2-hot gather
        }
        int j = 0;
        for (; j + 32 <= m; j += 32) {                // 4 gathers in flight
            #pragma unroll
            for (int kk = 0; kk < 4; ++kk) {
                int idx = j + 8 * kk + g;
                int   s  = __shfl(s_l, idx, 64);
                float nm = __shfl(nm_l, idx, 64);
                gacc8(hp, 8, s, ci, nm, acc);
            }
        }
        for (; j < m; j += 8) {                       // tail: <=7 padded edges
            int idx = j + g;
            int   s  = __shfl(s_l, idx, 64);
            float nm = __shfl(nm_l, idx, 64);
            gacc8(hp, 8, s, ci, nm, acc);
        }
    }
    #pragma unroll
    for (int q = 0; q < 8; ++q) {
        acc[q] += __shfl_xor(acc[q], 8, 64);
        acc[q] += __shfl_xor(acc[q], 16, 64);
        acc[q] += __shfl_xor(acc[q], 32, 64);
    }
    // self term folded: hn = q8 * ds2[node]; res = (acc + hn) * dd + b
    float hn[8];
    unq8(hp[(size_t)node * 8 + ci], ds2[node], hn);
    float4 b0 = *reinterpret_cast<const float4*>(b + 8 * ci);
    float4 b1v = *reinterpret_cast<const float4*>(b + 8 * ci + 4);
    const float bb[8] = {b0.x, b0.y, b0.z, b0.w, b1v.x, b1v.y, b1v.z, b1v.w};
    float res[8];
    #pragma unroll
    for (int q = 0; q < 8; ++q)
        res[q] = fmaf(acc[q] + hn[q], dd, bb[q]);

    float mx = res[0];
    #pragma unroll
    for (int q = 1; q < 8; ++q) mx = fmaxf(mx, res[q]);
    mx = fmaxf(mx, __shfl_xor(mx, 1, 64));
    mx = fmaxf(mx, __shfl_xor(mx, 2, 64));
    mx = fmaxf(mx, __shfl_xor(mx, 4, 64));
    float sm = 0.f;
    #pragma unroll
    for (int q = 0; q < 8; ++q) sm += expf(res[q] - mx);
    sm += __shfl_xor(sm, 1, 64);
    sm += __shfl_xor(sm, 2, 64);
    sm += __shfl_xor(sm, 4, 64);
    float lse = mx + logf(sm);
    if (g == 0) {
        float4 o0 = make_float4(res[0] - lse, res[1] - lse, res[2] - lse, res[3] - lse);
        float4 o1 = make_float4(res[4] - lse, res[5] - lse, res[6] - lse, res[7] - lse);
        *reinterpret_cast<float4*>(out + (size_t)node * 64 + 8 * ci)     = o0;
        *reinterpret_cast<float4*>(out + (size_t)node * 64 + 8 * ci + 4) = o1;
    }
}

extern "C" void kernel_launch(void* const* d_in, const int* in_sizes, int n_in,
                              void* d_out, int out_size, void* d_ws, size_t ws_size,
                              hipStream_t stream) {
    const float* x  = (const float*)d_in[0];
    const int*   ei = (const int*)d_in[1];     // [2,E]: src = ei[e], dst = ei[E+e]
    const float* w  = (const float*)d_in[2];
    const float* W1 = (const float*)d_in[3];
    const float* b1 = (const float*)d_in[4];
    const float* W2 = (const float*)d_in[5];
    const float* b2 = (const float*)d_in[6];
    float* out = (float*)d_out;

    const int N = in_sizes[0] / CH_IN;         // 50000 (< 65536: 16-bit packing valid)
    const int E = in_sizes[2];
    const int NBK = (N + 255) >> 8;            // buckets of 256 nodes (196)
    const int EPB = (E + NBLK1 - 1) / NBLK1;   // edges per count/scatter block
    const int WTB = (CH_HID * 128 + CH_OUT * 128 + 255) / 256;  // transpose blocks (96)

    // workspace carve (float units; uint2/int2 8B-aligned, bf16/int8 arrays 16B-aligned)
    float* ws0   = (float*)d_ws;
    float* ws    = ws0;
    float* dinv  = ws;               ws += N;
    float* scl1  = ws;               ws += N;
    float* ds1   = ws;               ws += N;
    float* ds2   = ws;               ws += N;
    int*   rowptr= (int*)ws;         ws += (N + 2);
    int*   cnt_bk= (int*)ws;         ws += 256 * NBLK1;
    int*   off_bk= (int*)ws;         ws += 256 * NBLK1;
    int*   btot  = (int*)ws;         ws += 256;
    uint2* ebuck = (uint2*)ws;       ws += (size_t)2 * E;
    int2*  epack = (int2*)ws;        ws += (size_t)2 * E;
    { size_t off = (size_t)(ws - ws0) & 3; if (off) ws += 4 - off; }   // 16B align
    unsigned short* w1t  = (unsigned short*)ws;  ws += (size_t)CH_HID * 128 / 2;
    unsigned short* w2t  = (unsigned short*)ws;  ws += (size_t)CH_OUT * 128 / 2;
    signed char*    h1q  = (signed char*)ws;     ws += (size_t)N * CH_HID / 4;   // int8 [N,128]
    unsigned short* out1 = (unsigned short*)ws;  ws += (size_t)N * CH_HID / 2;   // bf16 [N,128]
    signed char*    h2q  = (signed char*)ws;     ws += (size_t)N * CH_OUT / 4;   // int8 [N,64]

    const int B = 256;

    // 1) bucket count (atomic-free) ∥ weight transposes
    k_count<<<NBLK1 + WTB, B, 0, stream>>>(ei, cnt_bk, E, NBK, EPB, W1, w1t, W2, w2t);

    // 2) per-bucket cross-block scan
    k_bscan<<<NBK, 256, 0, stream>>>(cnt_bk, off_bk, btot);

    // 3) GEMM1 (int8 row-scaled out) co-scheduled with bucket scatter
    {
        const int nbg = (N + 63) / 64;
        k_fat<<<nbg + NBLK1, B, 0, stream>>>(x, w1t, h1q, scl1, N, nbg,
                                             ei, w, btot, off_bk, ebuck, E, NBK, EPB);
    }

    // 4) per-bucket CSR + dinv + ds1 + final epack
    k_csr<<<NBK, 256, 0, stream>>>(ebuck, btot, scl1, rowptr, dinv, ds1, epack, N, NBK);

    // 5) out1 = b1 + self + neighbor aggregate over int8 h1q (1 wave/node)
    k_agg128<<<(N * 64 + B - 1) / B, B, 0, stream>>>(rowptr, epack, dinv, ds1, h1q, b1, out1, N);

    // 6) h2q = int8(relu(out1) @ W2), ds2 = scl2*dinv
    k_gemm2<<<(N + 63) / 64, 256, 0, stream>>>(out1, w2t, dinv, h2q, ds2, N);

    // 7) out = log_softmax(b2 + self + aggregate over int8 h2q), fp32 into d_out
    k_agg64<<<(N * 64 + B - 1) / B, B, 0, stream>>>(rowptr, epack, dinv, ds2, h2q, b2, out, N);
}